// Round 9
// baseline (159.566 us; speedup 1.0000x reference)
//
#include <hip/hip_runtime.h>
#include <hip/hip_bf16.h>

#define Dn 20000
#define Bn 32

typedef short bf8_t __attribute__((ext_vector_type(8)));   // 8 bf16 in 4 VGPRs
typedef float f32x4 __attribute__((ext_vector_type(4)));

static __device__ __forceinline__ short f2bf(float f) {
    __hip_bfloat16 h = __float2bfloat16(f);
    return __builtin_bit_cast(short, h);
}

// ws layout (floats):
//   FjT     : [128][20000]  at 0
//   partial : [1250][512]   at 2,560,000
//   base    : [32][128]     at 3,200,000

// ---------------- B (fused A1 + MFMA stage1+2): per 16-d chunk
// Phase 1: cooperative F1 tile [16][128] in LDS (17 FMA per entry).
// Phase 2: 4 waves (bhalf = w&1, dsub = w>>1), mfma_f32_16x16x32_bf16 over k,
//          per-d epilogue applies b2/relu/mask, accumulates into cacc[4].
__global__ __launch_bounds__(256) void kB(const float* __restrict__ x,
                                          const int* __restrict__ mask,
                                          const float* __restrict__ F_embed,
                                          const float* __restrict__ f_bias,
                                          const float* __restrict__ W1,
                                          const float* __restrict__ b1,
                                          const float* __restrict__ W2,
                                          const float* __restrict__ b2,
                                          float* __restrict__ partial)
{
    const int t = threadIdx.x;
    const int w = t >> 6;
    const int l = t & 63;
    const int bhalf = w & 1;
    const int dsub  = w >> 1;
    const int d0 = blockIdx.x * 16;            // 1250*16 = 20000 exact

    __shared__ float f1s[16][128];  // 8 KB, row stride 128 (reads are 16-lane broadcast)
    __shared__ float fes[16][17];   // F_embed rows + f_bias in col 16
    __shared__ float xs[528];       // xs[dl*33 + b]
    __shared__ float ms[528];
    __shared__ float red[512];

    // ---- stage F_embed / f_bias / x / mask
    {
        const int dl = t >> 4, i = t & 15;
        fes[dl][i] = F_embed[(size_t)(d0 + dl) * 16 + i];
        if (t < 16) fes[t][16] = f_bias[d0 + t];
    }
#pragma unroll
    for (int i = 0; i < 2; ++i) {
        const int idx = t + i * 256;
        const int dl = idx & 15, b = idx >> 4;
        xs[dl * 33 + b] = x[b * Dn + d0 + dl];
        ms[dl * 33 + b] = (float)mask[b * Dn + d0 + dl];
    }

    // per-lane frag constants (no LDS dependency)
    const int ko = (l >> 4) * 8;               // k-octet base within a 32-k step
    float w1f[4][8];
#pragma unroll
    for (int s = 0; s < 4; ++s)
#pragma unroll
        for (int e = 0; e < 8; ++e) w1f[s][e] = W1[s * 32 + ko + e];
    bf8_t bfr[4];
#pragma unroll
    for (int s = 0; s < 4; ++s)
#pragma unroll
        for (int e = 0; e < 8; ++e) bfr[s][e] = f2bf(W2[(s * 32 + ko + e) * 16 + (l & 15)]);
    const float b2v = b2[l & 15];

    __syncthreads();

    // ---- phase 1: F1 tile (fused kA1): 2048 entries, 8 per thread
#pragma unroll
    for (int e = 0; e < 8; ++e) {
        const int idx = t + e * 256;
        const int dl = idx >> 7, k = idx & 127;
        float acc = fmaf(fes[dl][16], W1[17 * 128 + k], b1[k]);
#pragma unroll
        for (int i = 0; i < 16; ++i) acc = fmaf(fes[dl][i], W1[(1 + i) * 128 + k], acc);
        f1s[dl][k] = acc;
    }
    __syncthreads();

    // ---- phase 2: MFMA over 8 d's per wave
    f32x4 cacc = {0.f, 0.f, 0.f, 0.f};
    for (int i = 0; i < 8; ++i) {
        const int dl = dsub * 8 + i;
        const float xv = xs[dl * 33 + bhalf * 16 + (l & 15)];
        f32x4 acc = {0.f, 0.f, 0.f, 0.f};
#pragma unroll
        for (int s = 0; s < 4; ++s) {
            const float4 fa = *(const float4*)(&f1s[dl][s * 32 + ko]);
            const float4 fb = *(const float4*)(&f1s[dl][s * 32 + ko + 4]);
            bf8_t af;
            af[0] = f2bf(fmaxf(fmaf(xv, w1f[s][0], fa.x), 0.f));
            af[1] = f2bf(fmaxf(fmaf(xv, w1f[s][1], fa.y), 0.f));
            af[2] = f2bf(fmaxf(fmaf(xv, w1f[s][2], fa.z), 0.f));
            af[3] = f2bf(fmaxf(fmaf(xv, w1f[s][3], fa.w), 0.f));
            af[4] = f2bf(fmaxf(fmaf(xv, w1f[s][4], fb.x), 0.f));
            af[5] = f2bf(fmaxf(fmaf(xv, w1f[s][5], fb.y), 0.f));
            af[6] = f2bf(fmaxf(fmaf(xv, w1f[s][6], fb.z), 0.f));
            af[7] = f2bf(fmaxf(fmaf(xv, w1f[s][7], fb.w), 0.f));
            acc = __builtin_amdgcn_mfma_f32_16x16x32_bf16(af, bfr[s], acc, 0, 0, 0);
        }
        // lane holds C[m=(l>>4)*4+r][n=l&15]; b = bhalf*16 + m
#pragma unroll
        for (int r = 0; r < 4; ++r) {
            const float mvr = ms[dl * 33 + bhalf * 16 + (l >> 4) * 4 + r];
            cacc[r] = fmaf(mvr, fmaxf(acc[r] + b2v, 0.f), cacc[r]);
        }
    }

    // combine dsub halves in LDS, write block partial
    const int base = bhalf * 256 + (l >> 4) * 64 + (l & 15);
    if (dsub == 0) {
        red[base]      = cacc[0];
        red[base + 16] = cacc[1];
        red[base + 32] = cacc[2];
        red[base + 48] = cacc[3];
    }
    __syncthreads();
    if (dsub == 1) {
        red[base]      += cacc[0];
        red[base + 16] += cacc[1];
        red[base + 32] += cacc[2];
        red[base + 48] += cacc[3];
    }
    __syncthreads();
    float* __restrict__ po = partial + blockIdx.x * 512;
    po[t]       = red[t];
    po[t + 256] = red[t + 256];
}

// ---------------- C (fused R): per-b block: reduce partials -> c -> henc -> enc -> pz -> base_j
__global__ __launch_bounds__(256) void kC(const float* __restrict__ partial,
                                          const float* __restrict__ We1,
                                          const float* __restrict__ be1,
                                          const float* __restrict__ We2,
                                          const float* __restrict__ be2,
                                          const float* __restrict__ Wz,
                                          const float* __restrict__ bz,
                                          const float* __restrict__ Wj1,
                                          const float* __restrict__ bj1,
                                          float* __restrict__ out,
                                          float* __restrict__ basews)
{
    const int b = blockIdx.x;
    const int t = threadIdx.x;
    __shared__ float rsum[16][17];
    __shared__ float cb[16];
    __shared__ float henc[256];
    __shared__ float ep[4][64];
    __shared__ float zl[32];
    __shared__ float pzl[128];
    __shared__ float jp[2][128];

    // fused kR: sum partial[r][b*16 + j] over r
    {
        const int j = t & 15, g = t >> 4;
        float s = 0.f;
        for (int r = g; r < 1250; r += 16) s += partial[r * 512 + b * 16 + j];
        rsum[g][j] = s;
    }
    __syncthreads();
    if (t < 16) {
        float a = 0.f;
#pragma unroll
        for (int g = 0; g < 16; ++g) a += rsum[g][t];
        cb[t] = a;
    }
    __syncthreads();

    // E1: henc[t] = relu(c @ We1 + be1)
    {
        float a = be1[t];
#pragma unroll
        for (int i = 0; i < 16; ++i) a = fmaf(cb[i], We1[i * 256 + t], a);
        henc[t] = fmaxf(a, 0.f);
    }
    __syncthreads();

    // E2: enc = henc @ We2 + be2, split-K over 4 groups
    {
        const int o = t & 63, s = t >> 6;
        float a = 0.f;
#pragma unroll 8
        for (int i = 0; i < 64; ++i) a = fmaf(henc[s * 64 + i], We2[(s * 64 + i) * 64 + o], a);
        ep[s][o] = a;
    }
    __syncthreads();
    if (t < 64) {
        const float e = be2[t] + ep[0][t] + ep[1][t] + ep[2][t] + ep[3][t];
        if (t < 32) { out[640000 + b * 32 + t] = e; zl[t] = e; }   // mu (= z)
        else        { out[641024 + b * 32 + (t - 32)] = e; }       // logvar
    }
    __syncthreads();

    // Z: pz = relu(z @ Wz + bz)
    if (t < 128) {
        float a = bz[t];
#pragma unroll 8
        for (int i = 0; i < 32; ++i) a = fmaf(zl[i], Wz[i * 128 + t], a);
        pzl[t] = fmaxf(a, 0.f);
    }
    __syncthreads();

    // J: base = pz @ Wj1[:128] + bj1, split-K over 2 groups
    {
        const int k = t & 127, s = t >> 7;
        float a = 0.f;
#pragma unroll 8
        for (int i = 0; i < 64; ++i) a = fmaf(pzl[s * 64 + i], Wj1[(s * 64 + i) * 128 + k], a);
        jp[s][k] = a;
    }
    __syncthreads();
    if (t < 128) basews[b * 128 + t] = bj1[t] + jp[0][t] + jp[1][t];
}

// ---------------- A2: FjT[k][d] = f_bias[d]*Wj1[144][k] + sum_i F_embed[d][i]*Wj1[128+i][k]
__global__ __launch_bounds__(256) void kA2(const float* __restrict__ F_embed,
                                           const float* __restrict__ f_bias,
                                           const float* __restrict__ Wj1,
                                           float* __restrict__ FjT)
{
    const int d  = blockIdx.x * 256 + threadIdx.x;
    const int kg = blockIdx.y * 8;
    if (d >= Dn) return;
    const float4* fe4 = (const float4*)(F_embed + d * 16);
    float fe[16];
    {
        float4 a = fe4[0], b = fe4[1], c = fe4[2], e = fe4[3];
        fe[0]=a.x; fe[1]=a.y; fe[2]=a.z; fe[3]=a.w;
        fe[4]=b.x; fe[5]=b.y; fe[6]=b.z; fe[7]=b.w;
        fe[8]=c.x; fe[9]=c.y; fe[10]=c.z; fe[11]=c.w;
        fe[12]=e.x; fe[13]=e.y; fe[14]=e.z; fe[15]=e.w;
    }
    const float fb = f_bias[d];
#pragma unroll
    for (int j = 0; j < 8; ++j) {
        const int k = kg + j;
        float acc = fb * Wj1[144 * 128 + k];
#pragma unroll
        for (int i = 0; i < 16; ++i) acc = fmaf(fe[i], Wj1[(128 + i) * 128 + k], acc);
        FjT[k * Dn + d] = acc;
    }
}

// ---------------- D: rec[b][d] = sum_k relu(base[b][k] + FjT[k][d]) * Wj2[k] + bj2
__global__ __launch_bounds__(256) void kD(const float* __restrict__ FjT,
                                          const float* __restrict__ basews,
                                          const float* __restrict__ Wj2,
                                          const float* __restrict__ bj2,
                                          float* __restrict__ rec)
{
    const int d  = blockIdx.x * 256 + threadIdx.x;
    const int bq = blockIdx.y * 4;
    if (d >= Dn) return;
    const float* __restrict__ bA = basews + (bq + 0) * 128;
    const float* __restrict__ bB = basews + (bq + 1) * 128;
    const float* __restrict__ bC = basews + (bq + 2) * 128;
    const float* __restrict__ bD = basews + (bq + 3) * 128;
    float a0 = 0.f, a1 = 0.f, a2 = 0.f, a3 = 0.f;
#pragma unroll 8
    for (int k = 0; k < 128; ++k) {
        const float fj = FjT[k * Dn + d];
        const float w  = Wj2[k];
        a0 = fmaf(fmaxf(fj + bA[k], 0.f), w, a0);
        a1 = fmaf(fmaxf(fj + bB[k], 0.f), w, a1);
        a2 = fmaf(fmaxf(fj + bC[k], 0.f), w, a2);
        a3 = fmaf(fmaxf(fj + bD[k], 0.f), w, a3);
    }
    const float bj = bj2[0];
    rec[(bq + 0) * Dn + d] = a0 + bj;
    rec[(bq + 1) * Dn + d] = a1 + bj;
    rec[(bq + 2) * Dn + d] = a2 + bj;
    rec[(bq + 3) * Dn + d] = a3 + bj;
}

extern "C" void kernel_launch(void* const* d_in, const int* in_sizes, int n_in,
                              void* d_out, int out_size, void* d_ws, size_t ws_size,
                              hipStream_t stream)
{
    const float* x       = (const float*)d_in[0];
    const int*   mask    = (const int*)d_in[1];
    const float* F_embed = (const float*)d_in[2];
    const float* f_bias  = (const float*)d_in[3];
    const float* W1      = (const float*)d_in[4];
    const float* b1      = (const float*)d_in[5];
    const float* W2      = (const float*)d_in[6];
    const float* b2      = (const float*)d_in[7];
    const float* We1     = (const float*)d_in[8];
    const float* be1     = (const float*)d_in[9];
    const float* We2     = (const float*)d_in[10];
    const float* be2     = (const float*)d_in[11];
    const float* Wz      = (const float*)d_in[12];
    const float* bz      = (const float*)d_in[13];
    const float* Wj1     = (const float*)d_in[14];
    const float* bj1     = (const float*)d_in[15];
    const float* Wj2     = (const float*)d_in[16];
    const float* bj2     = (const float*)d_in[17];
    float* out = (float*)d_out;
    float* ws  = (float*)d_ws;

    float* FjT     = ws;
    float* partial = ws + 2560000;
    float* basews  = ws + 3200000;

    kB <<<1250, 256, 0, stream>>>(x, mask, F_embed, f_bias, W1, b1, W2, b2, partial);
    kC <<<32,   256, 0, stream>>>(partial, We1, be1, We2, be2, Wz, bz, Wj1, bj1, out, basews);
    kA2<<<dim3(79, 16), 256, 0, stream>>>(F_embed, f_bias, Wj1, FjT);
    kD <<<dim3(79, 8),  256, 0, stream>>>(FjT, basews, Wj2, bj2, out);
}